// Round 2
// baseline (2373.411 us; speedup 1.0000x reference)
//
#include <hip/hip_runtime.h>

// ---------------------------------------------------------------------------
// RNN_Layer: x[B,T,C] fp32 -> conv1x1(w_in) -> dense(kernel) -> LSTM(rec)
//            -> dense(w_out).  B=32 T=1024 C=512 D=256 U=256 O=256.
// R8: recurrent GEMV on v_pk_fma_f16 (2cyc, 2 MAC) with op_sel h-broadcast.
//   R7 post-mortem: mfma_16x16x32 = ~19.4 cyc/SIMD -> GEMV via MFMA is
//   26 MAC/cyc/SIMD (row-waste 16x); dot2@~4cyc = 64; pk_fma@2cyc = 128.
// Per batch-WG (512 thr, 2 waves/SIMD = 256-VGPR budget): thread owns cols
// c0=tid, c1=tid+512; W packed as per-k (W[k][c0],W[k][c1]) f16 pairs.
// 192 k resident in VGPRs (asm-pinned); 64 k streamed from LDS (128 KiB),
// interleaved as block 3 of each 4 (16-reg ring, ~160cyc lead).
// h broadcast: uniform ds_read_b128 of f16 pairs; op_sel picks lo/hi.
// Gates: thread u has (i,g) of unit u; thread u+256 has (f,o) -> one float2
// LDS exchange, 2 lgkm-only barriers/step (no vmcnt drain).
// ---------------------------------------------------------------------------

#define DEV static __device__ __forceinline__

typedef __attribute__((ext_vector_type(8))) short short8;
typedef __attribute__((ext_vector_type(4))) float floatx4;
typedef _Float16 half2v __attribute__((ext_vector_type(2)));

static constexpr int Bsz = 32, T = 1024, C = 512, D = 256, U = 256, FU = 1024;
static constexpr int M = Bsz * T;   // 32768 rows for all GEMMs

DEV float bfu2f(unsigned int u) { union { unsigned int i; float f; } v; v.i = u; return v.f; }
DEV float bf2f(unsigned short u) { return bfu2f(((unsigned int)u) << 16); }
DEV unsigned short f2bf(float f) {
    union { float f; unsigned int i; } v; v.f = f;
    return (unsigned short)((v.i + 0x7fffu + ((v.i >> 16) & 1u)) >> 16);
}
DEV float sigmf(float x) { return 1.0f / (1.0f + __expf(-x)); }
DEV float tanhfast(float x) {
    const float a = __expf(-2.0f * fabsf(x));
    const float t = (1.0f - a) / (1.0f + a);
    return copysignf(t, x);
}

// fp32-or-bf16 element -> bf16 bit pattern (GEMM operand loads)
DEV short ld_bf(const float* p) { return (short)f2bf(*p); }
DEV short ld_bf(const unsigned short* p) { return (short)*p; }
DEV short8 ld_frag(const unsigned short* p) { return *(const short8*)p; }
DEV short8 ld_frag(const float* p) {
    short8 v;
#pragma unroll
    for (int j = 0; j < 8; j++) v[j] = (short)f2bf(p[j]);
    return v;
}
DEV float ldxz1(const float* p) { return *p; }
DEV float ldxz1(const unsigned short* p) { return bf2f(*p); }

// packed f16 fma with h-broadcast via op_sel:
//  PK_LO: acc.lo += w.lo*h.lo; acc.hi += w.hi*h.lo   (even k)
//  PK_HI: acc.lo += w.lo*h.hi; acc.hi += w.hi*h.hi   (odd k)
#define PK_LO(acc, w, h) \
    asm("v_pk_fma_f16 %0, %1, %2, %0 op_sel:[0,0,0] op_sel_hi:[1,0,1]" \
        : "+v"(acc) : "v"(w), "v"(h))
#define PK_HI(acc, w, h) \
    asm("v_pk_fma_f16 %0, %1, %2, %0 op_sel:[0,1,0] op_sel_hi:[1,1,1]" \
        : "+v"(acc) : "v"(w), "v"(h))

// lgkm-only barrier: cross-thread data is LDS-only; skip the vmcnt(0) drain
// that __syncthreads() would impose on the (thread-local) xz loads/hs stores.
#define BAR() asm volatile("s_waitcnt lgkmcnt(0)\n\ts_barrier" ::: "memory")

// ---------------------------------------------------------------------------
// Fragment-direct MFMA GEMM:  C[M,N] = A[M,K] @ B[K,N] + bias[N]
// One wave/block; wave owns NS 16-col strips (B frags in VGPRs), MT row tiles.
// Layouts (m89/m120-verified): A[m=lane&15][k=quad*8+j];
//   B[k=quad*8+j][n=lane&15]; D[m=quad*4+r][n=lane&15]
// ---------------------------------------------------------------------------
template <int K, int N, int MT, int NS, bool OUTF32, typename AT, typename BT>
__global__ __launch_bounds__(64) void gemm_mfma(
    const AT* __restrict__ A,
    const BT* __restrict__ Bm,
    const float* __restrict__ bias,
    void* __restrict__ Cv)
{
    constexpr int KC = K / 32;
    const int lane = threadIdx.x;
    const int quad = lane >> 4, lr = lane & 15;
    constexpr int NSG = N / (16 * NS);
    const int sg = blockIdx.x % NSG;
    const int mb = blockIdx.x / NSG;
    const int n0 = sg * 16 * NS;

    short8 bf[NS][KC];
    float biasv[NS];
#pragma unroll
    for (int s = 0; s < NS; s++) {
        const int n = n0 + s * 16 + lr;
        biasv[s] = bias[n];
#pragma unroll
        for (int kc = 0; kc < KC; kc++) {
            short8 v;
#pragma unroll
            for (int j = 0; j < 8; j++) {
                const int k = kc * 32 + quad * 8 + j;
                v[j] = ld_bf(&Bm[(size_t)k * N + n]);
            }
            bf[s][kc] = v;
        }
    }

    for (int mt = 0; mt < MT; mt++) {
        const int m0 = (mb * MT + mt) * 16;
        const AT* Ap = A + (size_t)(m0 + lr) * K + quad * 8;
        floatx4 acc[NS];
#pragma unroll
        for (int s = 0; s < NS; s++) acc[s] = (floatx4){0.f, 0.f, 0.f, 0.f};
#pragma unroll
        for (int kc = 0; kc < KC; kc++) {
            short8 af = ld_frag(Ap + kc * 32);
#pragma unroll
            for (int s = 0; s < NS; s++)
                acc[s] = __builtin_amdgcn_mfma_f32_16x16x32_bf16(af, bf[s][kc], acc[s], 0, 0, 0);
        }
#pragma unroll
        for (int s = 0; s < NS; s++) {
            const int n = n0 + s * 16 + lr;
#pragma unroll
            for (int r = 0; r < 4; r++) {
                const int m = m0 + quad * 4 + r;
                const float val = acc[s][r] + biasv[s];
                if (OUTF32)
                    ((float*)Cv)[(size_t)m * N + n] = val;
                else
                    ((unsigned short*)Cv)[(size_t)m * N + n] = f2bf(val);
            }
        }
    }
}

// ---------------------------------------------------------------------------
// Pack rec_kernel fp32 [256][1024] -> per-k f16 column pairs for pk_fma:
//   v(k,c) = ( f16 W[k][c], f16 W[k][c+512] ),  c in [0,512)
// Resident k (per 32-superblock, k%32 in [0,24)):  Pres[(s*24+b*8+e)*512+c]
// Streamed k (k%32 in [24,32)): Pst uint4-packed:  Pst[((s*2+p)*512+c)*4+e4]
//   where p=(k%8)>>2, e4=k&3 -> LDS tile Ws[j][tid] = 4 consecutive k.
// ---------------------------------------------------------------------------
__global__ __launch_bounds__(256) void pack_rec_pk(const float* __restrict__ rec,
                                                   unsigned int* __restrict__ Pres,
                                                   unsigned int* __restrict__ Pst)
{
    const int idx = blockIdx.x * 256 + threadIdx.x;   // 0..131071
    const int k = idx >> 9, c = idx & 511;
    const _Float16 lo = (_Float16)rec[(size_t)k * FU + c];
    const _Float16 hi = (_Float16)rec[(size_t)k * FU + c + 512];
    const unsigned int v = (unsigned int)__builtin_bit_cast(unsigned short, lo)
                         | ((unsigned int)__builtin_bit_cast(unsigned short, hi) << 16);
    const int s = k >> 5, e8 = k & 7, b3 = (k >> 3) & 3;
    if (b3 < 3)
        Pres[(size_t)(s * 24 + b3 * 8 + e8) * 512 + c] = v;
    else
        Pst[((size_t)(s * 2 + (e8 >> 2)) * 512 + c) * 4 + (e8 & 3)] = v;
}

// ---------------------------------------------------------------------------
// pk_fma LSTM. 1 WG (512 thr / 8 waves, 2 waves/SIMD) per batch.
// Per step per thread: 256 v_pk_fma_f16 (4 round-robin f16x2 chunk accs),
// 32 uniform b128 h reads, 16 b128 W-stream reads (2-superblock-lead ring).
// ---------------------------------------------------------------------------
template <typename XZT>
__global__ __attribute__((amdgpu_flat_work_group_size(512, 512),
                          amdgpu_waves_per_eu(2, 2)))
void lstm_pk(
    const XZT* __restrict__ xz,            // [B, T, 4U]
    const unsigned int* __restrict__ Pres, // resident W pairs [192][512]
    const uint4* __restrict__ Pst,         // streamed W pairs [16][512] uint4
    unsigned short* __restrict__ hs)       // [B, T, U] bf16 out
{
    const int b = blockIdx.x;
    const int tid = threadIdx.x;

    __shared__ uint4 Ws[16 * 512];                     // streamed W: 128 KiB
    __shared__ float2 zsh[U];                          // (sig f, sig o): 2 KiB
    __shared__ __align__(16) unsigned short hpk[2][U]; // h f16 dbuf: 1 KiB

    // stage streamed W (once)
#pragma unroll
    for (int j = 0; j < 16; j++) Ws[j * 512 + tid] = Pst[j * 512 + tid];
    if (tid < U) { hpk[0][tid] = 0; hpk[1][tid] = 0; }

    // resident W pairs k: per superblock s (32 k), the first 24 -> 192 VGPRs
    unsigned int Wr[192];
#pragma unroll
    for (int i = 0; i < 192; i++) Wr[i] = Pres[(size_t)i * 512 + tid];
#pragma unroll
    for (int i = 0; i < 192; i++) asm volatile("" : "+v"(Wr[i]));
    __syncthreads();

    const XZT* xzb = xz + (size_t)b * T * FU;
    unsigned short* hsb = hs + (size_t)b * T * U;

    float cst = 0.f;
    float xz0 = ldxz1(xzb + tid);
    float xz1 = ldxz1(xzb + tid + 512);

    for (int t = 0; t < T; t++) {
        // prefetch next step's xz (consumed at epilogue next iteration)
        float xz0n = 0.f, xz1n = 0.f;
        if (t + 1 < T) {
            xz0n = ldxz1(xzb + (size_t)(t + 1) * FU + tid);
            xz1n = ldxz1(xzb + (size_t)(t + 1) * FU + tid + 512);
        }

        const uint4* HP = (const uint4*)hpk[t & 1];    // 32 uniform h-pair quads
        unsigned int a0 = 0, a1 = 0, a2 = 0, a3 = 0;   // f16x2 chunk accs

        // stream ring: superblock sb consumes L[2*(sb&1)..], refilled 2 ahead
        uint4 L[4];
        L[0] = Ws[0 * 512 + tid]; L[1] = Ws[1 * 512 + tid];
        L[2] = Ws[2 * 512 + tid]; L[3] = Ws[3 * 512 + tid];

#pragma unroll
        for (int sb = 0; sb < 8; sb++) {
            // 3 resident 8-k blocks
#pragma unroll
            for (int bb = 0; bb < 3; bb++) {
                const uint4 hb = HP[sb * 4 + bb];
                const int w0 = sb * 24 + bb * 8;
                PK_LO(a0, Wr[w0 + 0], hb.x); PK_HI(a1, Wr[w0 + 1], hb.x);
                PK_LO(a2, Wr[w0 + 2], hb.y); PK_HI(a3, Wr[w0 + 3], hb.y);
                PK_LO(a0, Wr[w0 + 4], hb.z); PK_HI(a1, Wr[w0 + 5], hb.z);
                PK_LO(a2, Wr[w0 + 6], hb.w); PK_HI(a3, Wr[w0 + 7], hb.w);
            }
            // 1 streamed 8-k block (k = sb*32 + 24..31) from the LDS ring
            {
                const uint4 hb = HP[sb * 4 + 3];
                const uint4 wa = L[(sb & 1) * 2], wb = L[(sb & 1) * 2 + 1];
                PK_LO(a0, wa.x, hb.x); PK_HI(a1, wa.y, hb.x);
                PK_LO(a2, wa.z, hb.y); PK_HI(a3, wa.w, hb.y);
                PK_LO(a0, wb.x, hb.z); PK_HI(a1, wb.y, hb.z);
                PK_LO(a2, wb.z, hb.w); PK_HI(a3, wb.w, hb.w);
                if (sb < 6) {
                    L[(sb & 1) * 2]     = Ws[((sb + 2) * 2 + 0) * 512 + tid];
                    L[(sb & 1) * 2 + 1] = Ws[((sb + 2) * 2 + 1) * 512 + tid];
                }
            }
        }

        // epilogue: unpack chunk accumulators (f16 -> f32) and add xz
        float z0 = xz0, z1 = xz1;
        {
            half2v p;
            p = __builtin_bit_cast(half2v, a0); z0 += (float)p[0]; z1 += (float)p[1];
            p = __builtin_bit_cast(half2v, a1); z0 += (float)p[0]; z1 += (float)p[1];
            p = __builtin_bit_cast(half2v, a2); z0 += (float)p[0]; z1 += (float)p[1];
            p = __builtin_bit_cast(half2v, a3); z0 += (float)p[0]; z1 += (float)p[1];
        }

        // gates: thread u has (z_i, z_g) of unit u; thread u+256 has (z_f, z_o)
        if (tid >= U) zsh[tid - U] = make_float2(sigmf(z0), sigmf(z1));
        BAR();
        if (tid < U) {
            const float2 fo = zsh[tid];
            const float iv = sigmf(z0);
            const float gv = tanhfast(z1);
            cst = fo.x * cst + iv * gv;
            const float hv = fo.y * tanhfast(cst);
            hpk[(t + 1) & 1][tid] = __builtin_bit_cast(unsigned short, (_Float16)hv);
            hsb[(size_t)t * U + tid] = f2bf(hv);
        }
        BAR();

        xz0 = xz0n; xz1 = xz1n;
    }
}

// ---------------------------------------------------------------------------
extern "C" void kernel_launch(void* const* d_in, const int* in_sizes, int n_in,
                              void* d_out, int out_size, void* d_ws, size_t ws_size,
                              hipStream_t stream)
{
    const float* x    = (const float*)d_in[0];
    const float* w_in = (const float*)d_in[1];
    const float* b_in = (const float*)d_in[2];
    const float* kern = (const float*)d_in[3];
    const float* rec  = (const float*)d_in[4];
    const float* bias = (const float*)d_in[5];
    const float* wout = (const float*)d_in[6];
    const float* bout = (const float*)d_in[7];

    char* ws = (char*)d_ws;
    const size_t rec_bytes = (size_t)512 * 1024;          // 384K Pres + 128K Pst
    const size_t xin_bytes = (size_t)M * D * 2;           // 16 MiB
    const size_t hs_bytes  = (size_t)M * U * 2;           // 16 MiB
    const size_t xz32_bytes = (size_t)M * FU * 4;         // 128 MiB
    const size_t base = rec_bytes + xin_bytes + hs_bytes;

    unsigned int* Pres = (unsigned int*)ws;
    unsigned int* Pst  = (unsigned int*)(ws + (size_t)384 * 1024);
    unsigned short* xin_bf = (unsigned short*)(ws + rec_bytes);
    unsigned short* hs_bf  = (unsigned short*)(ws + rec_bytes + xin_bytes);
    char* xz_raw = ws + base;

    const bool use_f32 = ws_size >= base + xz32_bytes;

    // pack rec_kernel -> f16 column-pair layout (every launch; ws re-poisoned)
    pack_rec_pk<<<512, 256, 0, stream>>>(rec, Pres, Pst);

    // GEMM1: xin = bf16(x @ w_in + b_in)   [M,512]x[512,256]
    gemm_mfma<512, 256, 16, 2, false><<<(256 / 32) * (M / 256), 64, 0, stream>>>(
        x, w_in, b_in, (void*)xin_bf);

    if (use_f32) {
        float* xzp = (float*)xz_raw;
        // GEMM2: xz = fp32(xin @ kernel + bias)  [M,256]x[256,1024]
        gemm_mfma<256, 1024, 16, 2, true><<<(1024 / 32) * (M / 256), 64, 0, stream>>>(
            xin_bf, kern, bias, (void*)xzp);
        lstm_pk<float><<<Bsz, 512, 0, stream>>>(xzp, Pres, (const uint4*)Pst, hs_bf);
    } else {
        unsigned short* xzp = (unsigned short*)xz_raw;
        gemm_mfma<256, 1024, 16, 2, false><<<(1024 / 32) * (M / 256), 64, 0, stream>>>(
            xin_bf, kern, bias, (void*)xzp);
        lstm_pk<unsigned short><<<Bsz, 512, 0, stream>>>(xzp, Pres, (const uint4*)Pst, hs_bf);
    }

    // GEMM3: out = fp32(hs @ w_out + b_out)  [M,256]x[256,256]
    gemm_mfma<256, 256, 16, 2, true><<<(256 / 32) * (M / 256), 64, 0, stream>>>(
        hs_bf, wout, bout, d_out);
}